// Round 10
// baseline (200.559 us; speedup 1.0000x reference)
//
#include <hip/hip_runtime.h>
#include <math.h>

#define NN 8192
#define CF 192
#define KNN 9
#define NSPL 8

__device__ __forceinline__ int group_start(int g) {
    // smallest i with batch[i]==g :  ceil(8191*g/8), capped at 8192
    int s = (8191 * g + 7) >> 3;
    return s > 8192 ? 8192 : s;
}

__device__ __forceinline__ float disf(int d) {
    return d > 0 ? 1.0f / sqrtf((float)d) : 0.0f;
}

__device__ __forceinline__ unsigned short f2bf(float f) {
    unsigned u = __float_as_uint(f);
    unsigned r = (u + 0x7FFFu + ((u >> 16) & 1u)) >> 16;   // round-nearest-even
    return (unsigned short)r;
}
__device__ __forceinline__ float bf2f(unsigned short h) {
    return __uint_as_float(((unsigned)h) << 16);
}

// ---------------------------------------------------------------- transpose + sq
// x [8,192,32,32] -> xf [8192][192]; also accumulates sq[node] = ||x_f||^2
// via per-32-channel partial sums (half-wave shuffle reduce + atomicAdd).
// sq must be zeroed before launch (memsetAsync covers sq+deg).
__global__ __launch_bounds__(256) void transpose_kernel(
    const float* __restrict__ x, float* __restrict__ xf, float* __restrict__ sq)
{
    __shared__ float tile[32][65];
    int b = blockIdx.x, ct = blockIdx.y, ht = blockIdx.z;
    int c0 = ct * 32, hw0 = ht * 64;
    int tid = threadIdx.x;
#pragma unroll
    for (int p = 0; p < 8; ++p) {
        int c  = p * 4 + (tid >> 6);
        int hw = tid & 63;
        tile[c][hw] = x[(size_t)b * 196608 + (size_t)(c0 + c) * 1024 + hw0 + hw];
    }
    __syncthreads();
#pragma unroll
    for (int p = 0; p < 8; ++p) {
        int hw = p * 8 + (tid >> 5);
        int cc = tid & 31;
        float v = tile[cc][hw];
        xf[(size_t)(b * 1024 + hw0 + hw) * CF + c0 + cc] = v;
        float s = v * v;                 // partial ||.||^2 over this 32-ch slice
#pragma unroll
        for (int off = 16; off > 0; off >>= 1) s += __shfl_xor(s, off, 64);
        if (cc == 0) atomicAdd(&sq[b * 1024 + hw0 + hw], s);
    }
}

// ---------------------------------------------------------------- kNN partial
// grid: 9 groups x 16 query-blocks(64 q) x 8 candidate-splits(128 c) = 1152
// blocks of 128 threads (2 waves). 1024 heavy blocks = 4/CU (LDS 23 KB
// allows 7) -> 2x the independent blocks/CU of Round 9 for phase overlap.
// 8x8 micro-tile (ty rows, tx cols {tx*4, 64+tx*4}) keeps LDS at 1.0 B/FMA.
// Round-7 lesson: selection loops fully unrolled, acc[][] statically indexed.
__global__ __launch_bounds__(128, 2) void knn_kernel(
    const float* __restrict__ xf, const float* __restrict__ sq,
    float* __restrict__ pk_d, int* __restrict__ pk_i)
{
    int bid = blockIdx.x;
    int g = bid >> 7;
    int rem = bid & 127;
    int qb = rem >> 3;
    int split = rem & 7;
    int gs = group_start(g);
    int gsize = group_start(g + 1) - gs;
    int q0 = qb * 64;
    int nq = gsize - q0; if (nq > 64) nq = 64;
    if (nq <= 0) return;                 // block-uniform; q's covered elsewhere
    int c0 = split * 128;
    int ncc = gsize - c0; if (ncc > 128) ncc = 128;

    int tid = threadIdx.x;

    float td[KNN]; int ti[KNN];
#pragma unroll
    for (int j = 0; j < KNN; ++j) { td[j] = __builtin_inff(); ti[j] = -1; }

    if (ncc <= 0) {                      // block-uniform: empty split
        if (tid < nq) {
            int q = gs + q0 + tid;
            size_t base = ((size_t)q * NSPL + split) * KNN;
#pragma unroll
            for (int j = 0; j < KNN; ++j) { pk_d[base + j] = td[j]; pk_i[base + j] = ti[j]; }
        }
        return;
    }

    // staging region (12800 B), overlaid by phase-1 partial lists (9360 B)
    __shared__ __align__(16) char smem[12800];
    float (*As)[68]  = (float(*)[68])smem;                    // 16x68x4  = 4352
    float (*Bs)[132] = (float(*)[132])(smem + 4352);          // 16x132x4 = 8448
    float (*ld)[KNN][65] = (float(*)[KNN][65])smem;           // 2x9x65x4 = 4680
    int   (*li)[KNN][65] = (int(*)[KNN][65])(smem + 4680);    // 4680
    __shared__ float Ds[64][37];         // one 32-col quarter at a time (9472)
    __shared__ float sqc_s[128];
    __shared__ float sqq_s[64];

    int ty = tid >> 4;                   // row group: rows ty*8 .. +7 (8 groups)
    int tx = tid & 15;                   // cols tx*4 (h0), 64+tx*4 (h1)

    if (tid < 64) {
        int qo = q0 + tid; if (qo > gsize - 1) qo = gsize - 1;
        sqq_s[tid] = sq[gs + qo];
    }
    {
        int co = c0 + tid;
        sqc_s[tid] = (tid < ncc) ? sq[gs + co] : __builtin_inff();
    }

    float acc[8][8];
#pragma unroll
    for (int i = 0; i < 8; ++i)
#pragma unroll
        for (int j = 0; j < 8; ++j) acc[i][j] = 0.0f;

    for (int kb = 0; kb < 12; ++kb) {
        __syncthreads();
#pragma unroll
        for (int p = 0; p < 2; ++p) {    // As: 64 q-rows x 4 float4 = 256
            int t = tid + 128 * p;
            int r = t >> 2, c4 = (t & 3) * 4;
            int qo = q0 + r; if (qo > gsize - 1) qo = gsize - 1;
            float4 v = *(const float4*)(xf + (size_t)(gs + qo) * CF + kb * 16 + c4);
            As[c4 + 0][r] = v.x; As[c4 + 1][r] = v.y;
            As[c4 + 2][r] = v.z; As[c4 + 3][r] = v.w;
        }
#pragma unroll
        for (int p = 0; p < 4; ++p) {    // Bs: 128 c-rows x 4 float4 = 512
            int t = tid + 128 * p;
            int r = t >> 2, c4 = (t & 3) * 4;
            int co = c0 + r; if (co > gsize - 1) co = gsize - 1;
            float4 v = *(const float4*)(xf + (size_t)(gs + co) * CF + kb * 16 + c4);
            Bs[c4 + 0][r] = v.x; Bs[c4 + 1][r] = v.y;
            Bs[c4 + 2][r] = v.z; Bs[c4 + 3][r] = v.w;
        }
        __syncthreads();
#pragma unroll
        for (int k = 0; k < 16; ++k) {
            float4 a0 = *(const float4*)&As[k][ty * 8];
            float4 a1 = *(const float4*)&As[k][ty * 8 + 4];
            float4 b0 = *(const float4*)&Bs[k][tx * 4];
            float4 b1 = *(const float4*)&Bs[k][64 + tx * 4];
            float aa[8] = {a0.x, a0.y, a0.z, a0.w, a1.x, a1.y, a1.z, a1.w};
            float bb[8] = {b0.x, b0.y, b0.z, b0.w, b1.x, b1.y, b1.z, b1.w};
#pragma unroll
            for (int i = 0; i < 8; ++i)
#pragma unroll
                for (int j = 0; j < 8; ++j)
                    acc[i][j] = fmaf(aa[i], bb[j], acc[i][j]);
        }
    }

    // ---- selection over four 32-column quarters (candidates in index order)
    // qtr loop UNROLLED: every acc[][] index must be compile-time constant.
#pragma unroll
    for (int qtr = 0; qtr < 4; ++qtr) {
        __syncthreads();                 // FMA/phase2 reads done
        // quarter's dot products: cols 32*qtr .. +31. Owner threads:
        // tx>>3 == (qtr&1); acc cols from half (qtr>>1).
        if ((tx >> 3) == (qtr & 1)) {
#pragma unroll
            for (int i = 0; i < 8; ++i) {
                float4 v = (qtr < 2)
                    ? make_float4(acc[i][0], acc[i][1], acc[i][2], acc[i][3])
                    : make_float4(acc[i][4], acc[i][5], acc[i][6], acc[i][7]);
                *(float4*)&Ds[ty * 8 + i][(tx & 7) * 4] = v;
            }
        }
        __syncthreads();
        // phase1: thread -> (query q = tid&63, chunk ch = tid>>6 of 16 cands)
        {
            int q = tid & 63, ch = tid >> 6;
            float sqq = sqq_s[q];
            float pd[KNN]; int pi[KNN];
#pragma unroll
            for (int j = 0; j < KNN; ++j) { pd[j] = __builtin_inff(); pi[j] = -1; }
            for (int j16 = 0; j16 < 16; ++j16) {
                int c = ch * 16 + j16;
                float d = (sqq - 2.0f * Ds[q][c]) + sqc_s[qtr * 32 + c];  // inf pad
                if (d < pd[KNN - 1]) {
                    pd[KNN - 1] = d; pi[KNN - 1] = gs + c0 + qtr * 32 + c;
#pragma unroll
                    for (int j = KNN - 1; j > 0; --j) {
                        if (pd[j] < pd[j - 1]) {
                            float tf = pd[j]; pd[j] = pd[j - 1]; pd[j - 1] = tf;
                            int tn = pi[j]; pi[j] = pi[j - 1]; pi[j - 1] = tn;
                        }
                    }
                }
            }
#pragma unroll
            for (int j = 0; j < KNN; ++j) { ld[ch][j][q] = pd[j]; li[ch][j][q] = pi[j]; }
        }
        __syncthreads();
        // phase2: 64 threads merge 2 sorted lists (index order; early break)
        if (tid < 64) {
            for (int ch = 0; ch < 2; ++ch) {
#pragma unroll
                for (int j0 = 0; j0 < KNN; ++j0) {
                    float d = ld[ch][j0][tid];
                    if (!(d < td[KNN - 1])) break;   // sorted: rest can't insert
                    int id = li[ch][j0][tid];
                    td[KNN - 1] = d; ti[KNN - 1] = id;
#pragma unroll
                    for (int j = KNN - 1; j > 0; --j) {
                        if (td[j] < td[j - 1]) {
                            float tf = td[j]; td[j] = td[j - 1]; td[j - 1] = tf;
                            int tn = ti[j]; ti[j] = ti[j - 1]; ti[j - 1] = tn;
                        }
                    }
                }
            }
        }
    }

    if (tid < nq) {
        int q = gs + q0 + tid;
        size_t base = ((size_t)q * NSPL + split) * KNN;
#pragma unroll
        for (int j = 0; j < KNN; ++j) { pk_d[base + j] = td[j]; pk_i[base + j] = ti[j]; }
    }
}

// ---------------------------------------------------------------- merge + deg
__global__ __launch_bounds__(256) void merge_kernel(
    const float* __restrict__ pk_d, const int* __restrict__ pk_i,
    int* __restrict__ edges, int* __restrict__ deg)
{
    int q = blockIdx.x * 256 + threadIdx.x;
    if (q >= NN) return;
    float td[KNN]; int ti[KNN];
#pragma unroll
    for (int j = 0; j < KNN; ++j) { td[j] = __builtin_inff(); ti[j] = -1; }
    for (int s = 0; s < NSPL; ++s) {       // split order = index order (stable)
        size_t base = ((size_t)q * NSPL + s) * KNN;
#pragma unroll
        for (int j0 = 0; j0 < KNN; ++j0) {
            float d = pk_d[base + j0];
            if (!(d < td[KNN - 1])) break;   // lists sorted: rest can't insert
            int id = pk_i[base + j0];
            td[KNN - 1] = d; ti[KNN - 1] = id;
#pragma unroll
            for (int j = KNN - 1; j > 0; --j) {
                if (td[j] < td[j - 1]) {
                    float tf = td[j]; td[j] = td[j - 1]; td[j - 1] = tf;
                    int tn = ti[j]; ti[j] = ti[j - 1]; ti[j - 1] = tn;
                }
            }
        }
    }
#pragma unroll
    for (int j = 0; j < KNN; ++j) {
        int id = ti[j];                   // -1 <=> invalid (d == inf)
        edges[q * KNN + j] = id;
        if (id >= 0 && id != q) atomicAdd(&deg[id], 1);
    }
}

// ---------------------------------------------------------------- fused Tx1 + out GEMM
// One block per 16-row stripe (512 blocks). LDS staging in bf16 (halves the
// LDS bytes/FMA that bound this kernel); fp32 accumulate + fp32 epilogue.
// Paired-k reads: Axh pairs over k (b32), Wsh pairs over adjacent cols (b32).
// LDS 25.7 KB.
__global__ __launch_bounds__(256, 2) void out_kernel(
    const float* __restrict__ xf, const int* __restrict__ edges,
    const int* __restrict__ deg, const float* __restrict__ W0,
    const float* __restrict__ W1, const float* __restrict__ bias,
    float* __restrict__ out)
{
    __shared__ unsigned short Axh[2][16][CF];   // [0]=xf, [1]=Tx1 (12288 B)
    __shared__ unsigned short Wsh[2][16][CF];   // W0/W1 k-tiles  (12288 B)
    __shared__ float coef_s[16][KNN];
    __shared__ int   nb_s[16][KNN];

    int r0 = blockIdx.x * 16;
    int tid = threadIdx.x;

    // W prefetch setup: 1536 float4 per kb tile, 6 per thread (fp32 load,
    // bf16 convert on LDS store)
    const float* wsrc[6];
    int ww[6], wr[6], wc[6];
    float4 pw[6];
#pragma unroll
    for (int p = 0; p < 6; ++p) {
        int f = p * 256 + tid;
        ww[p] = f / 768; wr[p] = (f % 768) / 48; wc[p] = (f % 48) * 4;
        wsrc[p] = (ww[p] ? W1 : W0) + (size_t)wr[p] * CF + wc[p];
        pw[p] = *(const float4*)(wsrc[p]);          // kb = 0
    }

    // stage xf rows -> bf16: 16 rows x 48 float4 = 768
    for (int t = tid; t < 768; t += 256) {
        int i = t / 48, c4 = (t % 48) * 4;
        float4 v = *(const float4*)&xf[(size_t)(r0 + i) * CF + c4];
        ushort4 h;
        h.x = f2bf(v.x); h.y = f2bf(v.y); h.z = f2bf(v.z); h.w = f2bf(v.w);
        *(ushort4*)&Axh[0][i][c4] = h;
    }
    // coefficients: one (row, edge) per thread
    if (tid < 16 * KNN) {
        int i = tid / KNN, j = tid % KNN;
        int q = r0 + i;
        int id = edges[q * KNN + j];
        float cf = 0.0f; int s = q;
        if (id >= 0 && id != q) { cf = -disf(deg[id]) * disf(deg[q]); s = id; }
        coef_s[i][j] = cf; nb_s[i][j] = s;
    }
    __syncthreads();
    // gather Tx1 rows -> bf16 pairs: 16*192/2 = 1536 pairs
    for (int e = tid; e < 16 * CF / 2; e += 256) {
        int i = e / 96, c2 = (e % 96) * 2;
        float a0 = 0.0f, a1 = 0.0f;
#pragma unroll
        for (int t = 0; t < KNN; ++t) {
            const float* row = xf + (size_t)nb_s[i][t] * CF + c2;
            float cf = coef_s[i][t];
            a0 = fmaf(cf, row[0], a0);
            a1 = fmaf(cf, row[1], a1);
        }
        ushort2 h; h.x = f2bf(a0); h.y = f2bf(a1);
        *(ushort2*)&Axh[1][i][c2] = h;
    }

    int ty = tid >> 5, tx = tid & 31;    // rows {ty*2,ty*2+1}, cols {tx*2+64m}
    float acc[2][6];
#pragma unroll
    for (int i = 0; i < 2; ++i)
#pragma unroll
        for (int j = 0; j < 6; ++j) acc[i][j] = 0.0f;

    for (int kb = 0; kb < 12; ++kb) {
        __syncthreads();                 // kb=0: Axh[1] ready; else Wsh consumed
#pragma unroll
        for (int p = 0; p < 6; ++p) {
            ushort4 h;
            h.x = f2bf(pw[p].x); h.y = f2bf(pw[p].y);
            h.z = f2bf(pw[p].z); h.w = f2bf(pw[p].w);
            *(ushort4*)&Wsh[ww[p]][wr[p]][wc[p]] = h;
        }
        __syncthreads();
        if (kb < 11) {
            size_t off = (size_t)(kb + 1) * 16 * CF;
#pragma unroll
            for (int p = 0; p < 6; ++p) pw[p] = *(const float4*)(wsrc[p] + off);
        }
#pragma unroll
        for (int k2 = 0; k2 < 8; ++k2) { // k = kb*16 + 2*k2 + {0,1}
            int kk = 2 * k2;
            ushort2 a0p = *(const ushort2*)&Axh[0][ty * 2 + 0][kb * 16 + kk];
            ushort2 a1p = *(const ushort2*)&Axh[0][ty * 2 + 1][kb * 16 + kk];
            ushort2 g0p = *(const ushort2*)&Axh[1][ty * 2 + 0][kb * 16 + kk];
            ushort2 g1p = *(const ushort2*)&Axh[1][ty * 2 + 1][kb * 16 + kk];
            float a0k0 = bf2f(a0p.x), a0k1 = bf2f(a0p.y);
            float a1k0 = bf2f(a1p.x), a1k1 = bf2f(a1p.y);
            float g0k0 = bf2f(g0p.x), g0k1 = bf2f(g0p.y);
            float g1k0 = bf2f(g1p.x), g1k1 = bf2f(g1p.y);
#pragma unroll
            for (int m = 0; m < 3; ++m) {
                ushort2 u00 = *(const ushort2*)&Wsh[0][kk + 0][tx * 2 + 64 * m];
                ushort2 u01 = *(const ushort2*)&Wsh[0][kk + 1][tx * 2 + 64 * m];
                ushort2 u10 = *(const ushort2*)&Wsh[1][kk + 0][tx * 2 + 64 * m];
                ushort2 u11 = *(const ushort2*)&Wsh[1][kk + 1][tx * 2 + 64 * m];
                float w00x = bf2f(u00.x), w00y = bf2f(u00.y);
                float w01x = bf2f(u01.x), w01y = bf2f(u01.y);
                float w10x = bf2f(u10.x), w10y = bf2f(u10.y);
                float w11x = bf2f(u11.x), w11y = bf2f(u11.y);
                acc[0][2*m+0] = fmaf(a0k0, w00x, acc[0][2*m+0]);
                acc[0][2*m+0] = fmaf(a0k1, w01x, acc[0][2*m+0]);
                acc[0][2*m+0] = fmaf(g0k0, w10x, acc[0][2*m+0]);
                acc[0][2*m+0] = fmaf(g0k1, w11x, acc[0][2*m+0]);
                acc[0][2*m+1] = fmaf(a0k0, w00y, acc[0][2*m+1]);
                acc[0][2*m+1] = fmaf(a0k1, w01y, acc[0][2*m+1]);
                acc[0][2*m+1] = fmaf(g0k0, w10y, acc[0][2*m+1]);
                acc[0][2*m+1] = fmaf(g0k1, w11y, acc[0][2*m+1]);
                acc[1][2*m+0] = fmaf(a1k0, w00x, acc[1][2*m+0]);
                acc[1][2*m+0] = fmaf(a1k1, w01x, acc[1][2*m+0]);
                acc[1][2*m+0] = fmaf(g1k0, w10x, acc[1][2*m+0]);
                acc[1][2*m+0] = fmaf(g1k1, w11x, acc[1][2*m+0]);
                acc[1][2*m+1] = fmaf(a1k0, w00y, acc[1][2*m+1]);
                acc[1][2*m+1] = fmaf(a1k1, w01y, acc[1][2*m+1]);
                acc[1][2*m+1] = fmaf(g1k0, w10y, acc[1][2*m+1]);
                acc[1][2*m+1] = fmaf(g1k1, w11y, acc[1][2*m+1]);
            }
        }
    }

#pragma unroll
    for (int i = 0; i < 2; ++i) {
        size_t ro = (size_t)(r0 + ty * 2 + i) * CF;
#pragma unroll
        for (int m = 0; m < 3; ++m) {
            float2 bv = *(const float2*)&bias[tx * 2 + 64 * m];
            float2 o;
            o.x = acc[i][2 * m + 0] + bv.x;
            o.y = acc[i][2 * m + 1] + bv.y;
            *(float2*)&out[ro + tx * 2 + 64 * m] = o;
        }
    }
}

// ---------------------------------------------------------------- launch
extern "C" void kernel_launch(void* const* d_in, const int* in_sizes, int n_in,
                              void* d_out, int out_size, void* d_ws, size_t ws_size,
                              hipStream_t stream)
{
    const float* x    = (const float*)d_in[0];
    const float* W0   = (const float*)d_in[1];
    const float* W1   = (const float*)d_in[2];
    const float* bias = (const float*)d_in[3];
    float* out = (float*)d_out;

    // Workspace: 6.65 MB (known-safe). sq and deg adjacent -> one memset.
    char* ws = (char*)d_ws;
    float* xf    = (float*)ws;  ws += (size_t)NN * CF * 4;   // 6,291,456
    float* sq    = (float*)ws;  ws += (size_t)NN * 4;        //    32,768
    int*   deg   = (int*)ws;    ws += (size_t)NN * 4;        //    32,768
    int*   edges = (int*)ws;    ws += (size_t)NN * KNN * 4;  //   294,912

    // Partial top-k lists live in d_out (4.72 MB of its 6.29 MB); d_out is
    // fully overwritten by out_kernel afterwards, every call.
    float* pk_d = out;                                       // NN*NSPL*KNN
    int*   pk_i = (int*)(out + (size_t)NN * NSPL * KNN);     // NN*NSPL*KNN

    hipMemsetAsync(sq, 0, (size_t)NN * 8, stream);           // sq + deg
    hipLaunchKernelGGL(transpose_kernel, dim3(8, 6, 16), dim3(256), 0, stream, x, xf, sq);
    hipLaunchKernelGGL(knn_kernel, dim3(1152), dim3(128), 0, stream, xf, sq, pk_d, pk_i);
    hipLaunchKernelGGL(merge_kernel, dim3(32), dim3(256), 0, stream, pk_d, pk_i, edges, deg);
    hipLaunchKernelGGL(out_kernel, dim3(512), dim3(256), 0, stream,
                       xf, edges, deg, W0, W1, bias, out);
}

// Round 11
// 162.238 us; speedup vs baseline: 1.2362x; 1.2362x over previous
//
#include <hip/hip_runtime.h>
#include <math.h>

#define NN 8192
#define CF 192
#define KNN 9
#define NSPL 4

typedef __bf16 v8bf __attribute__((ext_vector_type(8)));
typedef float f32x16 __attribute__((ext_vector_type(16)));

__device__ __forceinline__ int group_start(int g) {
    // smallest i with batch[i]==g :  ceil(8191*g/8), capped at 8192
    int s = (8191 * g + 7) >> 3;
    return s > 8192 ? 8192 : s;
}

__device__ __forceinline__ float disf(int d) {
    return d > 0 ? 1.0f / sqrtf((float)d) : 0.0f;
}

__device__ __forceinline__ unsigned short f2bf(float f) {
    unsigned u = __float_as_uint(f);
    unsigned r = (u + 0x7FFFu + ((u >> 16) & 1u)) >> 16;   // round-nearest-even
    return (unsigned short)r;
}
__device__ __forceinline__ float bf2f(unsigned short h) {
    return __uint_as_float(((unsigned)h) << 16);
}

// ---------------------------------------------------------------- transpose + sq
// x [8,192,32,32] -> xf [8192][192]; also accumulates sq[node] = ||x_f||^2
// via per-32-channel partial sums (half-wave shuffle reduce + atomicAdd).
// sq must be zeroed before launch (memsetAsync covers sq+deg).
__global__ __launch_bounds__(256) void transpose_kernel(
    const float* __restrict__ x, float* __restrict__ xf, float* __restrict__ sq)
{
    __shared__ float tile[32][65];
    int b = blockIdx.x, ct = blockIdx.y, ht = blockIdx.z;
    int c0 = ct * 32, hw0 = ht * 64;
    int tid = threadIdx.x;
#pragma unroll
    for (int p = 0; p < 8; ++p) {
        int c  = p * 4 + (tid >> 6);
        int hw = tid & 63;
        tile[c][hw] = x[(size_t)b * 196608 + (size_t)(c0 + c) * 1024 + hw0 + hw];
    }
    __syncthreads();
#pragma unroll
    for (int p = 0; p < 8; ++p) {
        int hw = p * 8 + (tid >> 5);
        int cc = tid & 31;
        float v = tile[cc][hw];
        xf[(size_t)(b * 1024 + hw0 + hw) * CF + c0 + cc] = v;
        float s = v * v;                 // partial ||.||^2 over this 32-ch slice
#pragma unroll
        for (int off = 16; off > 0; off >>= 1) s += __shfl_xor(s, off, 64);
        if (cc == 0) atomicAdd(&sq[b * 1024 + hw0 + hw], s);
    }
}

// ---------------------------------------------------------------- kNN partial (MFMA)
// grid: 9 groups x 16 query-blocks(64 q) x 4 candidate-splits(256 c) = 576
// blocks of 256 threads. Gram via v_mfma_f32_32x32x16_bf16 with SPLIT-BF16
// (x = hi+lo; dot = hi*hi + lo*hi + hi*lo, ~2^-17 rel err = fp32-class).
// A and B operands both read row-major rows (row=lane&31, k=(lane>>5)*8+j);
// any k-permutation cancels between A and B. C/D layout (HW-verified):
// col=lane&31, row=(reg&3)+8*(reg>>2)+4*(lane>>5).
// Wave w: q-tile (w&1)*32, c-tiles (w>>1)*128 + t*32, t=0..3 -> acc[4] f32x16.
// Selection = Round-9 proven path (Ds stride 69 quarters). Round-7 lesson:
// every acc index is compile-time constant (unrolled qt/s/r loops).
__global__ __launch_bounds__(256, 2) void knn_kernel(
    const float* __restrict__ xf, const float* __restrict__ sq,
    float* __restrict__ pk_d, int* __restrict__ pk_i)
{
    int bid = blockIdx.x;
    int g = bid >> 6;
    int rem = bid & 63;
    int qb = rem >> 2;
    int split = rem & 3;
    int gs = group_start(g);
    int gsize = group_start(g + 1) - gs;
    int q0 = qb * 64;
    int nq = gsize - q0; if (nq > 64) nq = 64;
    if (nq <= 0) return;                 // block-uniform; q's covered elsewhere
    int c0 = split * 256;
    int ncc = gsize - c0; if (ncc > 256) ncc = 256;

    int tid = threadIdx.x;

    float td[KNN]; int ti[KNN];
#pragma unroll
    for (int j = 0; j < KNN; ++j) { td[j] = __builtin_inff(); ti[j] = -1; }

    if (ncc <= 0) {                      // block-uniform: empty split
        if (tid < nq) {
            int q = gs + q0 + tid;
            size_t base = ((size_t)q * NSPL + split) * KNN;
#pragma unroll
            for (int j = 0; j < KNN; ++j) { pk_d[base + j] = td[j]; pk_i[base + j] = ti[j]; }
        }
        return;
    }

    // staging (alive in K loop, 30720 B), overlaid by phase-1 lists (18720 B)
    __shared__ __align__(16) char smem[30720];
    unsigned short (*Ah)[24] = (unsigned short(*)[24])smem;            // 64x24x2 = 3072
    unsigned short (*Al)[24] = (unsigned short(*)[24])(smem + 3072);   // 3072
    unsigned short (*Bh)[24] = (unsigned short(*)[24])(smem + 6144);   // 256x24x2 = 12288
    unsigned short (*Bl)[24] = (unsigned short(*)[24])(smem + 18432);  // 12288
    float (*ld)[KNN][65] = (float(*)[KNN][65])smem;                    // 4x9x65x4 = 9360
    int   (*li)[KNN][65] = (int(*)[KNN][65])(smem + 9360);             // 9360
    __shared__ float Ds[64][69];         // one 64-col quarter at a time
    __shared__ float sqc_s[256];
    __shared__ float sqq_s[64];

    int lane = tid & 63, w = tid >> 6;
    int arow = (w & 1) * 32 + (lane & 31);
    int k8 = (lane >> 5) * 8;
    int brow0 = (w >> 1) * 128 + (lane & 31);

    if (tid < 64) {
        int qo = q0 + tid; if (qo > gsize - 1) qo = gsize - 1;
        sqq_s[tid] = sq[gs + qo];
    }
    {
        int co = c0 + tid;
        sqc_s[tid] = (tid < ncc) ? sq[gs + co] : __builtin_inff();
    }

    f32x16 acc[4];
#pragma unroll
    for (int t = 0; t < 4; ++t)
#pragma unroll
        for (int r = 0; r < 16; ++r) acc[t][r] = 0.0f;

    for (int kb = 0; kb < 12; ++kb) {
        __syncthreads();
        {                                // As: 64 q-rows x 16 k (hi+lo)
            int r = tid >> 2, k4 = (tid & 3) * 4;
            int qo = q0 + r; if (qo > gsize - 1) qo = gsize - 1;
            float4 v = *(const float4*)(xf + (size_t)(gs + qo) * CF + kb * 16 + k4);
            ushort4 h, l;
            h.x = f2bf(v.x); l.x = f2bf(v.x - bf2f(h.x));
            h.y = f2bf(v.y); l.y = f2bf(v.y - bf2f(h.y));
            h.z = f2bf(v.z); l.z = f2bf(v.z - bf2f(h.z));
            h.w = f2bf(v.w); l.w = f2bf(v.w - bf2f(h.w));
            *(ushort4*)&Ah[r][k4] = h;
            *(ushort4*)&Al[r][k4] = l;
        }
#pragma unroll
        for (int p = 0; p < 4; ++p) {    // Bs: 256 c-rows x 16 k (hi+lo)
            int t = tid + 256 * p;
            int r = t >> 2, k4 = (t & 3) * 4;
            int co = c0 + r; if (co > gsize - 1) co = gsize - 1;
            float4 v = *(const float4*)(xf + (size_t)(gs + co) * CF + kb * 16 + k4);
            ushort4 h, l;
            h.x = f2bf(v.x); l.x = f2bf(v.x - bf2f(h.x));
            h.y = f2bf(v.y); l.y = f2bf(v.y - bf2f(h.y));
            h.z = f2bf(v.z); l.z = f2bf(v.z - bf2f(h.z));
            h.w = f2bf(v.w); l.w = f2bf(v.w - bf2f(h.w));
            *(ushort4*)&Bh[r][k4] = h;
            *(ushort4*)&Bl[r][k4] = l;
        }
        __syncthreads();
        v8bf a_hi = *(const v8bf*)&Ah[arow][k8];
        v8bf a_lo = *(const v8bf*)&Al[arow][k8];
#pragma unroll
        for (int t = 0; t < 4; ++t) {
            v8bf b_hi = *(const v8bf*)&Bh[brow0 + t * 32][k8];
            v8bf b_lo = *(const v8bf*)&Bl[brow0 + t * 32][k8];
            acc[t] = __builtin_amdgcn_mfma_f32_32x32x16_bf16(a_hi, b_hi, acc[t], 0, 0, 0);
            acc[t] = __builtin_amdgcn_mfma_f32_32x32x16_bf16(a_lo, b_hi, acc[t], 0, 0, 0);
            acc[t] = __builtin_amdgcn_mfma_f32_32x32x16_bf16(a_hi, b_lo, acc[t], 0, 0, 0);
        }
    }

    // ---- selection over four 64-column quarters (candidates in index order)
#pragma unroll
    for (int qt = 0; qt < 4; ++qt) {
        __syncthreads();                 // MFMA reads / prev phase2 done
        // quarter qt cols 64*qt..+63 = global c-tiles 2qt,2qt+1, owned by
        // waves with (w>>1)==(qt>>1); local tiles (qt&1)*2 + s.
        if ((w >> 1) == (qt >> 1)) {
#pragma unroll
            for (int s = 0; s < 2; ++s) {
#pragma unroll
                for (int r = 0; r < 16; ++r) {
                    int row = (w & 1) * 32 + (r & 3) + 8 * (r >> 2) + 4 * (lane >> 5);
                    Ds[row][s * 32 + (lane & 31)] = acc[(qt & 1) * 2 + s][r];
                }
            }
        }
        __syncthreads();
        // phase1: thread -> (query q = tid&63, chunk ch = tid>>6 of 16 cands)
        {
            int q = tid & 63, ch = tid >> 6;
            float sqq = sqq_s[q];
            float pd[KNN]; int pi[KNN];
#pragma unroll
            for (int j = 0; j < KNN; ++j) { pd[j] = __builtin_inff(); pi[j] = -1; }
            for (int j16 = 0; j16 < 16; ++j16) {
                int c = ch * 16 + j16;
                float d = (sqq - 2.0f * Ds[q][c]) + sqc_s[qt * 64 + c];  // inf pad
                if (d < pd[KNN - 1]) {
                    pd[KNN - 1] = d; pi[KNN - 1] = gs + c0 + qt * 64 + c;
#pragma unroll
                    for (int j = KNN - 1; j > 0; --j) {
                        if (pd[j] < pd[j - 1]) {
                            float tf = pd[j]; pd[j] = pd[j - 1]; pd[j - 1] = tf;
                            int tn = pi[j]; pi[j] = pi[j - 1]; pi[j - 1] = tn;
                        }
                    }
                }
            }
#pragma unroll
            for (int j = 0; j < KNN; ++j) { ld[ch][j][q] = pd[j]; li[ch][j][q] = pi[j]; }
        }
        __syncthreads();
        // phase2: 64 threads merge 4 sorted lists (index order; early break)
        if (tid < 64) {
            for (int ch = 0; ch < 4; ++ch) {
#pragma unroll
                for (int j0 = 0; j0 < KNN; ++j0) {
                    float d = ld[ch][j0][tid];
                    if (!(d < td[KNN - 1])) break;   // sorted: rest can't insert
                    int id = li[ch][j0][tid];
                    td[KNN - 1] = d; ti[KNN - 1] = id;
#pragma unroll
                    for (int j = KNN - 1; j > 0; --j) {
                        if (td[j] < td[j - 1]) {
                            float tf = td[j]; td[j] = td[j - 1]; td[j - 1] = tf;
                            int tn = ti[j]; ti[j] = ti[j - 1]; ti[j - 1] = tn;
                        }
                    }
                }
            }
        }
    }

    if (tid < nq) {
        int q = gs + q0 + tid;
        size_t base = ((size_t)q * NSPL + split) * KNN;
#pragma unroll
        for (int j = 0; j < KNN; ++j) { pk_d[base + j] = td[j]; pk_i[base + j] = ti[j]; }
    }
}

// ---------------------------------------------------------------- merge + deg
__global__ __launch_bounds__(256) void merge_kernel(
    const float* __restrict__ pk_d, const int* __restrict__ pk_i,
    int* __restrict__ edges, int* __restrict__ deg)
{
    int q = blockIdx.x * 256 + threadIdx.x;
    if (q >= NN) return;
    float td[KNN]; int ti[KNN];
#pragma unroll
    for (int j = 0; j < KNN; ++j) { td[j] = __builtin_inff(); ti[j] = -1; }
    for (int s = 0; s < NSPL; ++s) {       // split order = index order (stable)
        size_t base = ((size_t)q * NSPL + s) * KNN;
#pragma unroll
        for (int j0 = 0; j0 < KNN; ++j0) {
            float d = pk_d[base + j0];
            if (!(d < td[KNN - 1])) break;   // lists sorted: rest can't insert
            int id = pk_i[base + j0];
            td[KNN - 1] = d; ti[KNN - 1] = id;
#pragma unroll
            for (int j = KNN - 1; j > 0; --j) {
                if (td[j] < td[j - 1]) {
                    float tf = td[j]; td[j] = td[j - 1]; td[j - 1] = tf;
                    int tn = ti[j]; ti[j] = ti[j - 1]; ti[j - 1] = tn;
                }
            }
        }
    }
#pragma unroll
    for (int j = 0; j < KNN; ++j) {
        int id = ti[j];                   // -1 <=> invalid (d == inf)
        edges[q * KNN + j] = id;
        if (id >= 0 && id != q) atomicAdd(&deg[id], 1);
    }
}

// ---------------------------------------------------------------- fused Tx1 + out GEMM
// One block per 16-row stripe (512 blocks). LDS staging in bf16 (halves the
// LDS bytes/FMA that bound this kernel); fp32 accumulate + fp32 epilogue.
// Paired-k reads: Axh pairs over k (b32), Wsh pairs over adjacent cols (b32).
// LDS 25.7 KB.
__global__ __launch_bounds__(256, 2) void out_kernel(
    const float* __restrict__ xf, const int* __restrict__ edges,
    const int* __restrict__ deg, const float* __restrict__ W0,
    const float* __restrict__ W1, const float* __restrict__ bias,
    float* __restrict__ out)
{
    __shared__ unsigned short Axh[2][16][CF];   // [0]=xf, [1]=Tx1 (12288 B)
    __shared__ unsigned short Wsh[2][16][CF];   // W0/W1 k-tiles  (12288 B)
    __shared__ float coef_s[16][KNN];
    __shared__ int   nb_s[16][KNN];

    int r0 = blockIdx.x * 16;
    int tid = threadIdx.x;

    // W prefetch setup: 1536 float4 per kb tile, 6 per thread (fp32 load,
    // bf16 convert on LDS store)
    const float* wsrc[6];
    int ww[6], wr[6], wc[6];
    float4 pw[6];
#pragma unroll
    for (int p = 0; p < 6; ++p) {
        int f = p * 256 + tid;
        ww[p] = f / 768; wr[p] = (f % 768) / 48; wc[p] = (f % 48) * 4;
        wsrc[p] = (ww[p] ? W1 : W0) + (size_t)wr[p] * CF + wc[p];
        pw[p] = *(const float4*)(wsrc[p]);          // kb = 0
    }

    // stage xf rows -> bf16: 16 rows x 48 float4 = 768
    for (int t = tid; t < 768; t += 256) {
        int i = t / 48, c4 = (t % 48) * 4;
        float4 v = *(const float4*)&xf[(size_t)(r0 + i) * CF + c4];
        ushort4 h;
        h.x = f2bf(v.x); h.y = f2bf(v.y); h.z = f2bf(v.z); h.w = f2bf(v.w);
        *(ushort4*)&Axh[0][i][c4] = h;
    }
    // coefficients: one (row, edge) per thread
    if (tid < 16 * KNN) {
        int i = tid / KNN, j = tid % KNN;
        int q = r0 + i;
        int id = edges[q * KNN + j];
        float cf = 0.0f; int s = q;
        if (id >= 0 && id != q) { cf = -disf(deg[id]) * disf(deg[q]); s = id; }
        coef_s[i][j] = cf; nb_s[i][j] = s;
    }
    __syncthreads();
    // gather Tx1 rows -> bf16 pairs: 16*192/2 = 1536 pairs
    for (int e = tid; e < 16 * CF / 2; e += 256) {
        int i = e / 96, c2 = (e % 96) * 2;
        float a0 = 0.0f, a1 = 0.0f;
#pragma unroll
        for (int t = 0; t < KNN; ++t) {
            const float* row = xf + (size_t)nb_s[i][t] * CF + c2;
            float cf = coef_s[i][t];
            a0 = fmaf(cf, row[0], a0);
            a1 = fmaf(cf, row[1], a1);
        }
        ushort2 h; h.x = f2bf(a0); h.y = f2bf(a1);
        *(ushort2*)&Axh[1][i][c2] = h;
    }

    int ty = tid >> 5, tx = tid & 31;    // rows {ty*2,ty*2+1}, cols {tx*2+64m}
    float acc[2][6];
#pragma unroll
    for (int i = 0; i < 2; ++i)
#pragma unroll
        for (int j = 0; j < 6; ++j) acc[i][j] = 0.0f;

    for (int kb = 0; kb < 12; ++kb) {
        __syncthreads();                 // kb=0: Axh[1] ready; else Wsh consumed
#pragma unroll
        for (int p = 0; p < 6; ++p) {
            ushort4 h;
            h.x = f2bf(pw[p].x); h.y = f2bf(pw[p].y);
            h.z = f2bf(pw[p].z); h.w = f2bf(pw[p].w);
            *(ushort4*)&Wsh[ww[p]][wr[p]][wc[p]] = h;
        }
        __syncthreads();
        if (kb < 11) {
            size_t off = (size_t)(kb + 1) * 16 * CF;
#pragma unroll
            for (int p = 0; p < 6; ++p) pw[p] = *(const float4*)(wsrc[p] + off);
        }
#pragma unroll
        for (int k2 = 0; k2 < 8; ++k2) { // k = kb*16 + 2*k2 + {0,1}
            int kk = 2 * k2;
            ushort2 a0p = *(const ushort2*)&Axh[0][ty * 2 + 0][kb * 16 + kk];
            ushort2 a1p = *(const ushort2*)&Axh[0][ty * 2 + 1][kb * 16 + kk];
            ushort2 g0p = *(const ushort2*)&Axh[1][ty * 2 + 0][kb * 16 + kk];
            ushort2 g1p = *(const ushort2*)&Axh[1][ty * 2 + 1][kb * 16 + kk];
            float a0k0 = bf2f(a0p.x), a0k1 = bf2f(a0p.y);
            float a1k0 = bf2f(a1p.x), a1k1 = bf2f(a1p.y);
            float g0k0 = bf2f(g0p.x), g0k1 = bf2f(g0p.y);
            float g1k0 = bf2f(g1p.x), g1k1 = bf2f(g1p.y);
#pragma unroll
            for (int m = 0; m < 3; ++m) {
                ushort2 u00 = *(const ushort2*)&Wsh[0][kk + 0][tx * 2 + 64 * m];
                ushort2 u01 = *(const ushort2*)&Wsh[0][kk + 1][tx * 2 + 64 * m];
                ushort2 u10 = *(const ushort2*)&Wsh[1][kk + 0][tx * 2 + 64 * m];
                ushort2 u11 = *(const ushort2*)&Wsh[1][kk + 1][tx * 2 + 64 * m];
                float w00x = bf2f(u00.x), w00y = bf2f(u00.y);
                float w01x = bf2f(u01.x), w01y = bf2f(u01.y);
                float w10x = bf2f(u10.x), w10y = bf2f(u10.y);
                float w11x = bf2f(u11.x), w11y = bf2f(u11.y);
                acc[0][2*m+0] = fmaf(a0k0, w00x, acc[0][2*m+0]);
                acc[0][2*m+0] = fmaf(a0k1, w01x, acc[0][2*m+0]);
                acc[0][2*m+0] = fmaf(g0k0, w10x, acc[0][2*m+0]);
                acc[0][2*m+0] = fmaf(g0k1, w11x, acc[0][2*m+0]);
                acc[0][2*m+1] = fmaf(a0k0, w00y, acc[0][2*m+1]);
                acc[0][2*m+1] = fmaf(a0k1, w01y, acc[0][2*m+1]);
                acc[0][2*m+1] = fmaf(g0k0, w10y, acc[0][2*m+1]);
                acc[0][2*m+1] = fmaf(g0k1, w11y, acc[0][2*m+1]);
                acc[1][2*m+0] = fmaf(a1k0, w00x, acc[1][2*m+0]);
                acc[1][2*m+0] = fmaf(a1k1, w01x, acc[1][2*m+0]);
                acc[1][2*m+0] = fmaf(g1k0, w10x, acc[1][2*m+0]);
                acc[1][2*m+0] = fmaf(g1k1, w11x, acc[1][2*m+0]);
                acc[1][2*m+1] = fmaf(a1k0, w00y, acc[1][2*m+1]);
                acc[1][2*m+1] = fmaf(a1k1, w01y, acc[1][2*m+1]);
                acc[1][2*m+1] = fmaf(g1k0, w10y, acc[1][2*m+1]);
                acc[1][2*m+1] = fmaf(g1k1, w11y, acc[1][2*m+1]);
            }
        }
    }

#pragma unroll
    for (int i = 0; i < 2; ++i) {
        size_t ro = (size_t)(r0 + ty * 2 + i) * CF;
#pragma unroll
        for (int m = 0; m < 3; ++m) {
            float2 bv = *(const float2*)&bias[tx * 2 + 64 * m];
            float2 o;
            o.x = acc[i][2 * m + 0] + bv.x;
            o.y = acc[i][2 * m + 1] + bv.y;
            *(float2*)&out[ro + tx * 2 + 64 * m] = o;
        }
    }
}

// ---------------------------------------------------------------- launch
extern "C" void kernel_launch(void* const* d_in, const int* in_sizes, int n_in,
                              void* d_out, int out_size, void* d_ws, size_t ws_size,
                              hipStream_t stream)
{
    const float* x    = (const float*)d_in[0];
    const float* W0   = (const float*)d_in[1];
    const float* W1   = (const float*)d_in[2];
    const float* bias = (const float*)d_in[3];
    float* out = (float*)d_out;

    // Workspace: 6.65 MB (known-safe). sq and deg adjacent -> one memset.
    char* ws = (char*)d_ws;
    float* xf    = (float*)ws;  ws += (size_t)NN * CF * 4;   // 6,291,456
    float* sq    = (float*)ws;  ws += (size_t)NN * 4;        //    32,768
    int*   deg   = (int*)ws;    ws += (size_t)NN * 4;        //    32,768
    int*   edges = (int*)ws;    ws += (size_t)NN * KNN * 4;  //   294,912

    // Partial top-k lists live in d_out (2.36 MB of its 6.29 MB); d_out is
    // fully overwritten by out_kernel afterwards, every call.
    float* pk_d = out;                                       // NN*NSPL*KNN
    int*   pk_i = (int*)(out + (size_t)NN * NSPL * KNN);     // NN*NSPL*KNN

    hipMemsetAsync(sq, 0, (size_t)NN * 8, stream);           // sq + deg
    hipLaunchKernelGGL(transpose_kernel, dim3(8, 6, 16), dim3(256), 0, stream, x, xf, sq);
    hipLaunchKernelGGL(knn_kernel, dim3(576), dim3(256), 0, stream, xf, sq, pk_d, pk_i);
    hipLaunchKernelGGL(merge_kernel, dim3(32), dim3(256), 0, stream, pk_d, pk_i, edges, deg);
    hipLaunchKernelGGL(out_kernel, dim3(512), dim3(256), 0, stream,
                       xf, edges, deg, W0, W1, bias, out);
}

// Round 12
// 160.669 us; speedup vs baseline: 1.2483x; 1.0098x over previous
//
#include <hip/hip_runtime.h>
#include <math.h>

#define NN 8192
#define CF 192
#define KNN 9
#define NSPL 4

typedef __bf16 v8bf __attribute__((ext_vector_type(8)));
typedef float f32x16 __attribute__((ext_vector_type(16)));

__device__ __forceinline__ int group_start(int g) {
    // smallest i with batch[i]==g :  ceil(8191*g/8), capped at 8192
    int s = (8191 * g + 7) >> 3;
    return s > 8192 ? 8192 : s;
}

__device__ __forceinline__ float disf(int d) {
    return d > 0 ? 1.0f / sqrtf((float)d) : 0.0f;
}

__device__ __forceinline__ unsigned short f2bf(float f) {
    unsigned u = __float_as_uint(f);
    unsigned r = (u + 0x7FFFu + ((u >> 16) & 1u)) >> 16;   // round-nearest-even
    return (unsigned short)r;
}
__device__ __forceinline__ float bf2f(unsigned short h) {
    return __uint_as_float(((unsigned)h) << 16);
}

// ---------------------------------------------------------------- transpose + split + sq
// x [8,192,32,32] -> xh/xl [8192][192] bf16 (hi/lo split: v = hi + lo,
// computed ONCE here instead of 12x per element in knn staging).
// One block owns 64 nodes x all 192 ch -> sq computed locally (width-32
// shuffle reduce, no atomics, no memset); deg zeroed inline.
__global__ __launch_bounds__(256) void transpose_kernel(
    const float* __restrict__ x, unsigned short* __restrict__ xh,
    unsigned short* __restrict__ xl, float* __restrict__ sq,
    int* __restrict__ deg)
{
    __shared__ float tile[32][65];
    int b = blockIdx.x, ht = blockIdx.y;         // 8 x 16 blocks
    int hw0 = ht * 64;
    int tid = threadIdx.x;
    if (tid < 64) deg[(b * 16 + ht) * 64 + tid] = 0;

    float sacc[8];
#pragma unroll
    for (int p = 0; p < 8; ++p) sacc[p] = 0.0f;

    for (int ct = 0; ct < 6; ++ct) {
        int c0 = ct * 32;
        __syncthreads();
#pragma unroll
        for (int p = 0; p < 8; ++p) {
            int c  = p * 4 + (tid >> 6);
            int hw = tid & 63;
            tile[c][hw] = x[(size_t)b * 196608 + (size_t)(c0 + c) * 1024 + hw0 + hw];
        }
        __syncthreads();
#pragma unroll
        for (int p = 0; p < 8; ++p) {
            int hw = p * 8 + (tid >> 5);
            int cc = tid & 31;
            float v = tile[cc][hw];
            size_t o = (size_t)(b * 1024 + hw0 + hw) * CF + c0 + cc;
            unsigned short h = f2bf(v);
            xh[o] = h;
            xl[o] = f2bf(v - bf2f(h));
            sacc[p] = fmaf(v, v, sacc[p]);
        }
    }
#pragma unroll
    for (int p = 0; p < 8; ++p) {
        float s = sacc[p];
#pragma unroll
        for (int off = 16; off > 0; off >>= 1) s += __shfl_xor(s, off, 32);
        if ((tid & 31) == 0)
            sq[(size_t)(b * 1024 + hw0 + p * 8 + (tid >> 5))] = s;
    }
}

// ---------------------------------------------------------------- kNN partial (MFMA)
// grid: 9 groups x 16 query-blocks(64 q) x 4 candidate-splits(256 c) = 576
// blocks of 256 threads. Gram via v_mfma_f32_32x32x16_bf16 with SPLIT-BF16
// (dot = hi*hi + lo*hi + hi*lo, ~2^-17 rel err = fp32-class). hi/lo are
// PRECOMPUTED (xh/xl) -> staging is pure uint4 copy, zero converts.
// A/B operands both read row-major rows; k-permutation cancels A vs B.
// C/D layout (HW-verified): col=lane&31, row=(reg&3)+8*(reg>>2)+4*(lane>>5).
// Round-7 lesson: every acc index compile-time constant (unrolled loops).
__global__ __launch_bounds__(256, 2) void knn_kernel(
    const unsigned short* __restrict__ xh, const unsigned short* __restrict__ xl,
    const float* __restrict__ sq,
    float* __restrict__ pk_d, int* __restrict__ pk_i)
{
    int bid = blockIdx.x;
    int g = bid >> 6;
    int rem = bid & 63;
    int qb = rem >> 2;
    int split = rem & 3;
    int gs = group_start(g);
    int gsize = group_start(g + 1) - gs;
    int q0 = qb * 64;
    int nq = gsize - q0; if (nq > 64) nq = 64;
    if (nq <= 0) return;                 // block-uniform; q's covered elsewhere
    int c0 = split * 256;
    int ncc = gsize - c0; if (ncc > 256) ncc = 256;

    int tid = threadIdx.x;

    float td[KNN]; int ti[KNN];
#pragma unroll
    for (int j = 0; j < KNN; ++j) { td[j] = __builtin_inff(); ti[j] = -1; }

    if (ncc <= 0) {                      // block-uniform: empty split
        if (tid < nq) {
            int q = gs + q0 + tid;
            size_t base = ((size_t)q * NSPL + split) * KNN;
#pragma unroll
            for (int j = 0; j < KNN; ++j) { pk_d[base + j] = td[j]; pk_i[base + j] = ti[j]; }
        }
        return;
    }

    // staging (alive in K loop, 30720 B), overlaid by phase-1 lists (18720 B)
    __shared__ __align__(16) char smem[30720];
    unsigned short (*Ah)[24] = (unsigned short(*)[24])smem;            // 64x24x2 = 3072
    unsigned short (*Al)[24] = (unsigned short(*)[24])(smem + 3072);   // 3072
    unsigned short (*Bh)[24] = (unsigned short(*)[24])(smem + 6144);   // 256x24x2 = 12288
    unsigned short (*Bl)[24] = (unsigned short(*)[24])(smem + 18432);  // 12288
    float (*ld)[KNN][65] = (float(*)[KNN][65])smem;                    // 4x9x65x4 = 9360
    int   (*li)[KNN][65] = (int(*)[KNN][65])(smem + 9360);             // 9360
    __shared__ float Ds[64][69];         // one 64-col quarter at a time
    __shared__ float sqc_s[256];
    __shared__ float sqq_s[64];

    int lane = tid & 63, w = tid >> 6;
    int arow = (w & 1) * 32 + (lane & 31);
    int k8 = (lane >> 5) * 8;
    int brow0 = (w >> 1) * 128 + (lane & 31);

    if (tid < 64) {
        int qo = q0 + tid; if (qo > gsize - 1) qo = gsize - 1;
        sqq_s[tid] = sq[gs + qo];
    }
    {
        int co = c0 + tid;
        sqc_s[tid] = (tid < ncc) ? sq[gs + co] : __builtin_inff();
    }

    // per-thread staging roles (fixed across kb)
    int a_hl = tid >> 7, a_r = (tid >> 1) & 63, a_half = tid & 1;
    int a_qo = q0 + a_r; if (a_qo > gsize - 1) a_qo = gsize - 1;
    const unsigned short* a_src = (a_hl ? xl : xh)
        + (size_t)(gs + a_qo) * CF + a_half * 8;
    unsigned short* a_dst = (a_hl ? (unsigned short*)Al : (unsigned short*)Ah)
        + a_r * 24 + a_half * 8;

    f32x16 acc[4];
#pragma unroll
    for (int t = 0; t < 4; ++t)
#pragma unroll
        for (int r = 0; r < 16; ++r) acc[t][r] = 0.0f;

    for (int kb = 0; kb < 12; ++kb) {
        __syncthreads();
        *(uint4*)a_dst = *(const uint4*)(a_src + kb * 16);   // A hi/lo copy
#pragma unroll
        for (int p = 0; p < 4; ++p) {    // B tiles: 1024 x 16B copies
            int t = tid + 256 * p;
            int hl = t >> 9, r = (t >> 1) & 255, half = t & 1;
            int co = c0 + r; if (co > gsize - 1) co = gsize - 1;
            const unsigned short* src = (hl ? xl : xh)
                + (size_t)(gs + co) * CF + kb * 16 + half * 8;
            unsigned short* dst = (hl ? (unsigned short*)Bl : (unsigned short*)Bh)
                + r * 24 + half * 8;
            *(uint4*)dst = *(const uint4*)src;
        }
        __syncthreads();
        v8bf a_hi = *(const v8bf*)&Ah[arow][k8];
        v8bf a_lo = *(const v8bf*)&Al[arow][k8];
#pragma unroll
        for (int t = 0; t < 4; ++t) {
            v8bf b_hi = *(const v8bf*)&Bh[brow0 + t * 32][k8];
            v8bf b_lo = *(const v8bf*)&Bl[brow0 + t * 32][k8];
            acc[t] = __builtin_amdgcn_mfma_f32_32x32x16_bf16(a_hi, b_hi, acc[t], 0, 0, 0);
            acc[t] = __builtin_amdgcn_mfma_f32_32x32x16_bf16(a_lo, b_hi, acc[t], 0, 0, 0);
            acc[t] = __builtin_amdgcn_mfma_f32_32x32x16_bf16(a_hi, b_lo, acc[t], 0, 0, 0);
        }
    }

    // ---- selection over four 64-column quarters (candidates in index order)
#pragma unroll
    for (int qt = 0; qt < 4; ++qt) {
        __syncthreads();                 // MFMA reads / prev phase2 done
        // quarter qt cols 64*qt..+63 = global c-tiles 2qt,2qt+1, owned by
        // waves with (w>>1)==(qt>>1); local tiles (qt&1)*2 + s.
        if ((w >> 1) == (qt >> 1)) {
#pragma unroll
            for (int s = 0; s < 2; ++s) {
#pragma unroll
                for (int r = 0; r < 16; ++r) {
                    int row = (w & 1) * 32 + (r & 3) + 8 * (r >> 2) + 4 * (lane >> 5);
                    Ds[row][s * 32 + (lane & 31)] = acc[(qt & 1) * 2 + s][r];
                }
            }
        }
        __syncthreads();
        // phase1: thread -> (query q = tid&63, chunk ch = tid>>6 of 16 cands)
        {
            int q = tid & 63, ch = tid >> 6;
            float sqq = sqq_s[q];
            float pd[KNN]; int pi[KNN];
#pragma unroll
            for (int j = 0; j < KNN; ++j) { pd[j] = __builtin_inff(); pi[j] = -1; }
            for (int j16 = 0; j16 < 16; ++j16) {
                int c = ch * 16 + j16;
                float d = (sqq - 2.0f * Ds[q][c]) + sqc_s[qt * 64 + c];  // inf pad
                if (d < pd[KNN - 1]) {
                    pd[KNN - 1] = d; pi[KNN - 1] = gs + c0 + qt * 64 + c;
#pragma unroll
                    for (int j = KNN - 1; j > 0; --j) {
                        if (pd[j] < pd[j - 1]) {
                            float tf = pd[j]; pd[j] = pd[j - 1]; pd[j - 1] = tf;
                            int tn = pi[j]; pi[j] = pi[j - 1]; pi[j - 1] = tn;
                        }
                    }
                }
            }
#pragma unroll
            for (int j = 0; j < KNN; ++j) { ld[ch][j][q] = pd[j]; li[ch][j][q] = pi[j]; }
        }
        __syncthreads();
        // phase2: 64 threads merge 4 sorted lists (index order; early break)
        if (tid < 64) {
            for (int ch = 0; ch < 4; ++ch) {
#pragma unroll
                for (int j0 = 0; j0 < KNN; ++j0) {
                    float d = ld[ch][j0][tid];
                    if (!(d < td[KNN - 1])) break;   // sorted: rest can't insert
                    int id = li[ch][j0][tid];
                    td[KNN - 1] = d; ti[KNN - 1] = id;
#pragma unroll
                    for (int j = KNN - 1; j > 0; --j) {
                        if (td[j] < td[j - 1]) {
                            float tf = td[j]; td[j] = td[j - 1]; td[j - 1] = tf;
                            int tn = ti[j]; ti[j] = ti[j - 1]; ti[j - 1] = tn;
                        }
                    }
                }
            }
        }
    }

    if (tid < nq) {
        int q = gs + q0 + tid;
        size_t base = ((size_t)q * NSPL + split) * KNN;
#pragma unroll
        for (int j = 0; j < KNN; ++j) { pk_d[base + j] = td[j]; pk_i[base + j] = ti[j]; }
    }
}

// ---------------------------------------------------------------- merge + deg
// 128 blocks x 64 threads: spread the latency-bound scattered loads +
// atomics over 128 CUs (was 32 blocks -> only 32 CUs busy).
__global__ __launch_bounds__(64) void merge_kernel(
    const float* __restrict__ pk_d, const int* __restrict__ pk_i,
    int* __restrict__ edges, int* __restrict__ deg)
{
    int q = blockIdx.x * 64 + threadIdx.x;
    if (q >= NN) return;
    float td[KNN]; int ti[KNN];
#pragma unroll
    for (int j = 0; j < KNN; ++j) { td[j] = __builtin_inff(); ti[j] = -1; }
    for (int s = 0; s < NSPL; ++s) {       // split order = index order (stable)
        size_t base = ((size_t)q * NSPL + s) * KNN;
#pragma unroll
        for (int j0 = 0; j0 < KNN; ++j0) {
            float d = pk_d[base + j0];
            if (!(d < td[KNN - 1])) break;   // lists sorted: rest can't insert
            int id = pk_i[base + j0];
            td[KNN - 1] = d; ti[KNN - 1] = id;
#pragma unroll
            for (int j = KNN - 1; j > 0; --j) {
                if (td[j] < td[j - 1]) {
                    float tf = td[j]; td[j] = td[j - 1]; td[j - 1] = tf;
                    int tn = ti[j]; ti[j] = ti[j - 1]; ti[j - 1] = tn;
                }
            }
        }
    }
#pragma unroll
    for (int j = 0; j < KNN; ++j) {
        int id = ti[j];                   // -1 <=> invalid (d == inf)
        edges[q * KNN + j] = id;
        if (id >= 0 && id != q) atomicAdd(&deg[id], 1);
    }
}

// ---------------------------------------------------------------- fused Tx1 + out GEMM
// One block per 16-row stripe (512 blocks). A rows copied straight from xh
// (bf16, no convert); Tx1 gathered from bf16 rows (halves gather bytes).
// fp32 accumulate + fp32 epilogue. LDS 25.7 KB.
__global__ __launch_bounds__(256, 2) void out_kernel(
    const unsigned short* __restrict__ xh, const int* __restrict__ edges,
    const int* __restrict__ deg, const float* __restrict__ W0,
    const float* __restrict__ W1, const float* __restrict__ bias,
    float* __restrict__ out)
{
    __shared__ unsigned short Axh[2][16][CF];   // [0]=xf, [1]=Tx1 (12288 B)
    __shared__ unsigned short Wsh[2][16][CF];   // W0/W1 k-tiles  (12288 B)
    __shared__ float coef_s[16][KNN];
    __shared__ int   nb_s[16][KNN];

    int r0 = blockIdx.x * 16;
    int tid = threadIdx.x;

    // W prefetch setup: 1536 float4 per kb tile, 6 per thread (fp32 load,
    // bf16 convert on LDS store)
    const float* wsrc[6];
    int ww[6], wr[6], wc[6];
    float4 pw[6];
#pragma unroll
    for (int p = 0; p < 6; ++p) {
        int f = p * 256 + tid;
        ww[p] = f / 768; wr[p] = (f % 768) / 48; wc[p] = (f % 48) * 4;
        wsrc[p] = (ww[p] ? W1 : W0) + (size_t)wr[p] * CF + wc[p];
        pw[p] = *(const float4*)(wsrc[p]);          // kb = 0
    }

    // stage xf rows: straight bf16 copy, 16 rows x 24 uint4 = 384
    for (int t = tid; t < 384; t += 256) {
        int i = t / 24, c8 = (t % 24) * 8;
        *(uint4*)&Axh[0][i][c8] = *(const uint4*)(xh + (size_t)(r0 + i) * CF + c8);
    }
    // coefficients: one (row, edge) per thread
    if (tid < 16 * KNN) {
        int i = tid / KNN, j = tid % KNN;
        int q = r0 + i;
        int id = edges[q * KNN + j];
        float cf = 0.0f; int s = q;
        if (id >= 0 && id != q) { cf = -disf(deg[id]) * disf(deg[q]); s = id; }
        coef_s[i][j] = cf; nb_s[i][j] = s;
    }
    __syncthreads();
    // gather Tx1 rows from bf16 -> bf16 pairs: 16*192/2 = 1536 pairs
    for (int e = tid; e < 16 * CF / 2; e += 256) {
        int i = e / 96, c2 = (e % 96) * 2;
        float a0 = 0.0f, a1 = 0.0f;
#pragma unroll
        for (int t = 0; t < KNN; ++t) {
            const unsigned short* row = xh + (size_t)nb_s[i][t] * CF + c2;
            float cf = coef_s[i][t];
            a0 = fmaf(cf, bf2f(row[0]), a0);
            a1 = fmaf(cf, bf2f(row[1]), a1);
        }
        ushort2 h; h.x = f2bf(a0); h.y = f2bf(a1);
        *(ushort2*)&Axh[1][i][c2] = h;
    }

    int ty = tid >> 5, tx = tid & 31;    // rows {ty*2,ty*2+1}, cols {tx*2+64m}
    float acc[2][6];
#pragma unroll
    for (int i = 0; i < 2; ++i)
#pragma unroll
        for (int j = 0; j < 6; ++j) acc[i][j] = 0.0f;

    for (int kb = 0; kb < 12; ++kb) {
        __syncthreads();                 // kb=0: Axh[1] ready; else Wsh consumed
#pragma unroll
        for (int p = 0; p < 6; ++p) {
            ushort4 h;
            h.x = f2bf(pw[p].x); h.y = f2bf(pw[p].y);
            h.z = f2bf(pw[p].z); h.w = f2bf(pw[p].w);
            *(ushort4*)&Wsh[ww[p]][wr[p]][wc[p]] = h;
        }
        __syncthreads();
        if (kb < 11) {
            size_t off = (size_t)(kb + 1) * 16 * CF;
#pragma unroll
            for (int p = 0; p < 6; ++p) pw[p] = *(const float4*)(wsrc[p] + off);
        }
#pragma unroll
        for (int k2 = 0; k2 < 8; ++k2) { // k = kb*16 + 2*k2 + {0,1}
            int kk = 2 * k2;
            ushort2 a0p = *(const ushort2*)&Axh[0][ty * 2 + 0][kb * 16 + kk];
            ushort2 a1p = *(const ushort2*)&Axh[0][ty * 2 + 1][kb * 16 + kk];
            ushort2 g0p = *(const ushort2*)&Axh[1][ty * 2 + 0][kb * 16 + kk];
            ushort2 g1p = *(const ushort2*)&Axh[1][ty * 2 + 1][kb * 16 + kk];
            float a0k0 = bf2f(a0p.x), a0k1 = bf2f(a0p.y);
            float a1k0 = bf2f(a1p.x), a1k1 = bf2f(a1p.y);
            float g0k0 = bf2f(g0p.x), g0k1 = bf2f(g0p.y);
            float g1k0 = bf2f(g1p.x), g1k1 = bf2f(g1p.y);
#pragma unroll
            for (int m = 0; m < 3; ++m) {
                ushort2 u00 = *(const ushort2*)&Wsh[0][kk + 0][tx * 2 + 64 * m];
                ushort2 u01 = *(const ushort2*)&Wsh[0][kk + 1][tx * 2 + 64 * m];
                ushort2 u10 = *(const ushort2*)&Wsh[1][kk + 0][tx * 2 + 64 * m];
                ushort2 u11 = *(const ushort2*)&Wsh[1][kk + 1][tx * 2 + 64 * m];
                float w00x = bf2f(u00.x), w00y = bf2f(u00.y);
                float w01x = bf2f(u01.x), w01y = bf2f(u01.y);
                float w10x = bf2f(u10.x), w10y = bf2f(u10.y);
                float w11x = bf2f(u11.x), w11y = bf2f(u11.y);
                acc[0][2*m+0] = fmaf(a0k0, w00x, acc[0][2*m+0]);
                acc[0][2*m+0] = fmaf(a0k1, w01x, acc[0][2*m+0]);
                acc[0][2*m+0] = fmaf(g0k0, w10x, acc[0][2*m+0]);
                acc[0][2*m+0] = fmaf(g0k1, w11x, acc[0][2*m+0]);
                acc[0][2*m+1] = fmaf(a0k0, w00y, acc[0][2*m+1]);
                acc[0][2*m+1] = fmaf(a0k1, w01y, acc[0][2*m+1]);
                acc[0][2*m+1] = fmaf(g0k0, w10y, acc[0][2*m+1]);
                acc[0][2*m+1] = fmaf(g0k1, w11y, acc[0][2*m+1]);
                acc[1][2*m+0] = fmaf(a1k0, w00x, acc[1][2*m+0]);
                acc[1][2*m+0] = fmaf(a1k1, w01x, acc[1][2*m+0]);
                acc[1][2*m+0] = fmaf(g1k0, w10x, acc[1][2*m+0]);
                acc[1][2*m+0] = fmaf(g1k1, w11x, acc[1][2*m+0]);
                acc[1][2*m+1] = fmaf(a1k0, w00y, acc[1][2*m+1]);
                acc[1][2*m+1] = fmaf(a1k1, w01y, acc[1][2*m+1]);
                acc[1][2*m+1] = fmaf(g1k0, w10y, acc[1][2*m+1]);
                acc[1][2*m+1] = fmaf(g1k1, w11y, acc[1][2*m+1]);
            }
        }
    }

#pragma unroll
    for (int i = 0; i < 2; ++i) {
        size_t ro = (size_t)(r0 + ty * 2 + i) * CF;
#pragma unroll
        for (int m = 0; m < 3; ++m) {
            float2 bv = *(const float2*)&bias[tx * 2 + 64 * m];
            float2 o;
            o.x = acc[i][2 * m + 0] + bv.x;
            o.y = acc[i][2 * m + 1] + bv.y;
            *(float2*)&out[ro + tx * 2 + 64 * m] = o;
        }
    }
}

// ---------------------------------------------------------------- launch
extern "C" void kernel_launch(void* const* d_in, const int* in_sizes, int n_in,
                              void* d_out, int out_size, void* d_ws, size_t ws_size,
                              hipStream_t stream)
{
    const float* x    = (const float*)d_in[0];
    const float* W0   = (const float*)d_in[1];
    const float* W1   = (const float*)d_in[2];
    const float* bias = (const float*)d_in[3];
    float* out = (float*)d_out;

    // Workspace: 6,651,904 B (same total as the known-safe layout; fp32 xf
    // replaced by bf16 hi+lo planes).
    char* ws = (char*)d_ws;
    unsigned short* xh = (unsigned short*)ws; ws += (size_t)NN * CF * 2;  // 3,145,728
    unsigned short* xl = (unsigned short*)ws; ws += (size_t)NN * CF * 2;  // 3,145,728
    float* sq    = (float*)ws;  ws += (size_t)NN * 4;        //    32,768
    int*   deg   = (int*)ws;    ws += (size_t)NN * 4;        //    32,768
    int*   edges = (int*)ws;    ws += (size_t)NN * KNN * 4;  //   294,912

    // Partial top-k lists live in d_out (2.36 MB of its 6.29 MB); d_out is
    // fully overwritten by out_kernel afterwards, every call.
    float* pk_d = out;                                       // NN*NSPL*KNN
    int*   pk_i = (int*)(out + (size_t)NN * NSPL * KNN);     // NN*NSPL*KNN

    hipLaunchKernelGGL(transpose_kernel, dim3(8, 16), dim3(256), 0, stream,
                       x, xh, xl, sq, deg);
    hipLaunchKernelGGL(knn_kernel, dim3(576), dim3(256), 0, stream,
                       xh, xl, sq, pk_d, pk_i);
    hipLaunchKernelGGL(merge_kernel, dim3(128), dim3(64), 0, stream,
                       pk_d, pk_i, edges, deg);
    hipLaunchKernelGGL(out_kernel, dim3(512), dim3(256), 0, stream,
                       xh, edges, deg, W0, W1, bias, out);
}

// Round 13
// 154.035 us; speedup vs baseline: 1.3020x; 1.0431x over previous
//
#include <hip/hip_runtime.h>
#include <math.h>

#define NN 8192
#define CF 192
#define KNN 9
#define NSPL 4

typedef __bf16 v8bf __attribute__((ext_vector_type(8)));
typedef float f32x16 __attribute__((ext_vector_type(16)));
typedef float f32x4 __attribute__((ext_vector_type(4)));

__device__ __forceinline__ int group_start(int g) {
    // smallest i with batch[i]==g :  ceil(8191*g/8), capped at 8192
    int s = (8191 * g + 7) >> 3;
    return s > 8192 ? 8192 : s;
}

__device__ __forceinline__ float disf(int d) {
    return d > 0 ? 1.0f / sqrtf((float)d) : 0.0f;
}

__device__ __forceinline__ unsigned short f2bf(float f) {
    unsigned u = __float_as_uint(f);
    unsigned r = (u + 0x7FFFu + ((u >> 16) & 1u)) >> 16;   // round-nearest-even
    return (unsigned short)r;
}
__device__ __forceinline__ float bf2f(unsigned short h) {
    return __uint_as_float(((unsigned)h) << 16);
}

// ---------------------------------------------------------------- transpose + split + sq
// x [8,192,32,32] -> xh/xl [8192][192] bf16 (hi/lo split, computed once).
// One block owns 64 nodes x all 192 ch -> sq computed locally; deg zeroed.
__global__ __launch_bounds__(256) void transpose_kernel(
    const float* __restrict__ x, unsigned short* __restrict__ xh,
    unsigned short* __restrict__ xl, float* __restrict__ sq,
    int* __restrict__ deg)
{
    __shared__ float tile[32][65];
    int b = blockIdx.x, ht = blockIdx.y;         // 8 x 16 blocks
    int hw0 = ht * 64;
    int tid = threadIdx.x;
    if (tid < 64) deg[(b * 16 + ht) * 64 + tid] = 0;

    float sacc[8];
#pragma unroll
    for (int p = 0; p < 8; ++p) sacc[p] = 0.0f;

    for (int ct = 0; ct < 6; ++ct) {
        int c0 = ct * 32;
        __syncthreads();
#pragma unroll
        for (int p = 0; p < 8; ++p) {
            int c  = p * 4 + (tid >> 6);
            int hw = tid & 63;
            tile[c][hw] = x[(size_t)b * 196608 + (size_t)(c0 + c) * 1024 + hw0 + hw];
        }
        __syncthreads();
#pragma unroll
        for (int p = 0; p < 8; ++p) {
            int hw = p * 8 + (tid >> 5);
            int cc = tid & 31;
            float v = tile[cc][hw];
            size_t o = (size_t)(b * 1024 + hw0 + hw) * CF + c0 + cc;
            unsigned short h = f2bf(v);
            xh[o] = h;
            xl[o] = f2bf(v - bf2f(h));
            sacc[p] = fmaf(v, v, sacc[p]);
        }
    }
#pragma unroll
    for (int p = 0; p < 8; ++p) {
        float s = sacc[p];
#pragma unroll
        for (int off = 16; off > 0; off >>= 1) s += __shfl_xor(s, off, 32);
        if ((tid & 31) == 0)
            sq[(size_t)(b * 1024 + hw0 + p * 8 + (tid >> 5))] = s;
    }
}

// ---------------------------------------------------------------- kNN partial (MFMA)
// 576 blocks x 256 thr. Gram via split-bf16 32x32x16 MFMA (fp32-class err).
// NEW: register-prefetch pipeline — kb+1's 5x16B loads issue right after
// the staging barrier and drain during the 12 MFMAs. Safe now: (256,2)
// gives a 256-VGPR budget (Round-5 spill was under the (256,4)=64 budget).
// C/D layout (HW-verified): col=lane&31, row=(reg&3)+8*(reg>>2)+4*(lane>>5).
// Round-7 lesson: every acc index compile-time constant (unrolled loops).
__global__ __launch_bounds__(256, 2) void knn_kernel(
    const unsigned short* __restrict__ xh, const unsigned short* __restrict__ xl,
    const float* __restrict__ sq,
    float* __restrict__ pk_d, int* __restrict__ pk_i)
{
    int bid = blockIdx.x;
    int g = bid >> 6;
    int rem = bid & 63;
    int qb = rem >> 2;
    int split = rem & 3;
    int gs = group_start(g);
    int gsize = group_start(g + 1) - gs;
    int q0 = qb * 64;
    int nq = gsize - q0; if (nq > 64) nq = 64;
    if (nq <= 0) return;                 // block-uniform; q's covered elsewhere
    int c0 = split * 256;
    int ncc = gsize - c0; if (ncc > 256) ncc = 256;

    int tid = threadIdx.x;

    float td[KNN]; int ti[KNN];
#pragma unroll
    for (int j = 0; j < KNN; ++j) { td[j] = __builtin_inff(); ti[j] = -1; }

    if (ncc <= 0) {                      // block-uniform: empty split
        if (tid < nq) {
            int q = gs + q0 + tid;
            size_t base = ((size_t)q * NSPL + split) * KNN;
#pragma unroll
            for (int j = 0; j < KNN; ++j) { pk_d[base + j] = td[j]; pk_i[base + j] = ti[j]; }
        }
        return;
    }

    // staging (alive in K loop, 30720 B), overlaid by phase-1 lists (18720 B)
    __shared__ __align__(16) char smem[30720];
    unsigned short (*Ah)[24] = (unsigned short(*)[24])smem;            // 64x24x2 = 3072
    unsigned short (*Al)[24] = (unsigned short(*)[24])(smem + 3072);   // 3072
    unsigned short (*Bh)[24] = (unsigned short(*)[24])(smem + 6144);   // 256x24x2 = 12288
    unsigned short (*Bl)[24] = (unsigned short(*)[24])(smem + 18432);  // 12288
    float (*ld)[KNN][65] = (float(*)[KNN][65])smem;                    // 4x9x65x4 = 9360
    int   (*li)[KNN][65] = (int(*)[KNN][65])(smem + 9360);             // 9360
    __shared__ float Ds[64][69];         // one 64-col quarter at a time
    __shared__ float sqc_s[256];
    __shared__ float sqq_s[64];

    int lane = tid & 63, w = tid >> 6;
    int arow = (w & 1) * 32 + (lane & 31);
    int k8 = (lane >> 5) * 8;
    int brow0 = (w >> 1) * 128 + (lane & 31);

    if (tid < 64) {
        int qo = q0 + tid; if (qo > gsize - 1) qo = gsize - 1;
        sqq_s[tid] = sq[gs + qo];
    }
    {
        int co = c0 + tid;
        sqc_s[tid] = (tid < ncc) ? sq[gs + co] : __builtin_inff();
    }

    // per-thread staging roles (fixed across kb)
    int a_hl = tid >> 7, a_r = (tid >> 1) & 63, a_half = tid & 1;
    int a_qo = q0 + a_r; if (a_qo > gsize - 1) a_qo = gsize - 1;
    const unsigned short* a_src = (a_hl ? xl : xh)
        + (size_t)(gs + a_qo) * CF + a_half * 8;
    unsigned short* a_dst = (a_hl ? (unsigned short*)Al : (unsigned short*)Ah)
        + a_r * 24 + a_half * 8;
    const unsigned short* b_src[4];
    unsigned short* b_dst[4];
#pragma unroll
    for (int p = 0; p < 4; ++p) {
        int t = tid + 256 * p;
        int hl = t >> 9, r = (t >> 1) & 255, half = t & 1;
        int co = c0 + r; if (co > gsize - 1) co = gsize - 1;
        b_src[p] = (hl ? xl : xh) + (size_t)(gs + co) * CF + half * 8;
        b_dst[p] = (hl ? (unsigned short*)Bl : (unsigned short*)Bh) + r * 24 + half * 8;
    }

    // prefetch kb = 0
    uint4 pa = *(const uint4*)a_src;
    uint4 pb[4];
#pragma unroll
    for (int p = 0; p < 4; ++p) pb[p] = *(const uint4*)b_src[p];

    f32x16 acc[4];
#pragma unroll
    for (int t = 0; t < 4; ++t)
#pragma unroll
        for (int r = 0; r < 16; ++r) acc[t][r] = 0.0f;

    for (int kb = 0; kb < 12; ++kb) {
        __syncthreads();
        *(uint4*)a_dst = pa;
#pragma unroll
        for (int p = 0; p < 4; ++p) *(uint4*)b_dst[p] = pb[p];
        __syncthreads();
        if (kb < 11) {                   // issue kb+1 loads; drain during MFMA
            int off = (kb + 1) * 16;
            pa = *(const uint4*)(a_src + off);
#pragma unroll
            for (int p = 0; p < 4; ++p) pb[p] = *(const uint4*)(b_src[p] + off);
        }
        v8bf a_hi = *(const v8bf*)&Ah[arow][k8];
        v8bf a_lo = *(const v8bf*)&Al[arow][k8];
#pragma unroll
        for (int t = 0; t < 4; ++t) {
            v8bf b_hi = *(const v8bf*)&Bh[brow0 + t * 32][k8];
            v8bf b_lo = *(const v8bf*)&Bl[brow0 + t * 32][k8];
            acc[t] = __builtin_amdgcn_mfma_f32_32x32x16_bf16(a_hi, b_hi, acc[t], 0, 0, 0);
            acc[t] = __builtin_amdgcn_mfma_f32_32x32x16_bf16(a_lo, b_hi, acc[t], 0, 0, 0);
            acc[t] = __builtin_amdgcn_mfma_f32_32x32x16_bf16(a_hi, b_lo, acc[t], 0, 0, 0);
        }
    }

    // ---- selection over four 64-column quarters (candidates in index order)
#pragma unroll
    for (int qt = 0; qt < 4; ++qt) {
        __syncthreads();                 // MFMA reads / prev phase2 done
        if ((w >> 1) == (qt >> 1)) {
#pragma unroll
            for (int s = 0; s < 2; ++s) {
#pragma unroll
                for (int r = 0; r < 16; ++r) {
                    int row = (w & 1) * 32 + (r & 3) + 8 * (r >> 2) + 4 * (lane >> 5);
                    Ds[row][s * 32 + (lane & 31)] = acc[(qt & 1) * 2 + s][r];
                }
            }
        }
        __syncthreads();
        // phase1: thread -> (query q = tid&63, chunk ch = tid>>6 of 16 cands)
        {
            int q = tid & 63, ch = tid >> 6;
            float sqq = sqq_s[q];
            float pd[KNN]; int pi[KNN];
#pragma unroll
            for (int j = 0; j < KNN; ++j) { pd[j] = __builtin_inff(); pi[j] = -1; }
            for (int j16 = 0; j16 < 16; ++j16) {
                int c = ch * 16 + j16;
                float d = (sqq - 2.0f * Ds[q][c]) + sqc_s[qt * 64 + c];  // inf pad
                if (d < pd[KNN - 1]) {
                    pd[KNN - 1] = d; pi[KNN - 1] = gs + c0 + qt * 64 + c;
#pragma unroll
                    for (int j = KNN - 1; j > 0; --j) {
                        if (pd[j] < pd[j - 1]) {
                            float tf = pd[j]; pd[j] = pd[j - 1]; pd[j - 1] = tf;
                            int tn = pi[j]; pi[j] = pi[j - 1]; pi[j - 1] = tn;
                        }
                    }
                }
            }
#pragma unroll
            for (int j = 0; j < KNN; ++j) { ld[ch][j][q] = pd[j]; li[ch][j][q] = pi[j]; }
        }
        __syncthreads();
        // phase2: 64 threads merge 4 sorted lists (index order; early break)
        if (tid < 64) {
            for (int ch = 0; ch < 4; ++ch) {
#pragma unroll
                for (int j0 = 0; j0 < KNN; ++j0) {
                    float d = ld[ch][j0][tid];
                    if (!(d < td[KNN - 1])) break;   // sorted: rest can't insert
                    int id = li[ch][j0][tid];
                    td[KNN - 1] = d; ti[KNN - 1] = id;
#pragma unroll
                    for (int j = KNN - 1; j > 0; --j) {
                        if (td[j] < td[j - 1]) {
                            float tf = td[j]; td[j] = td[j - 1]; td[j - 1] = tf;
                            int tn = ti[j]; ti[j] = ti[j - 1]; ti[j - 1] = tn;
                        }
                    }
                }
            }
        }
    }

    if (tid < nq) {
        int q = gs + q0 + tid;
        size_t base = ((size_t)q * NSPL + split) * KNN;
#pragma unroll
        for (int j = 0; j < KNN; ++j) { pk_d[base + j] = td[j]; pk_i[base + j] = ti[j]; }
    }
}

// ---------------------------------------------------------------- merge + deg + W-transpose
// blocks 0..127: merge partial lists (64 q each). blocks 128..199: build
// bf16 W0^T/W1^T (n-major) into the dead xl region for out_kernel's MFMA
// B-fragments (fused here to avoid an extra dispatch).
__global__ __launch_bounds__(64) void merge_kernel(
    const float* __restrict__ pk_d, const int* __restrict__ pk_i,
    int* __restrict__ edges, int* __restrict__ deg,
    const float* __restrict__ W0, const float* __restrict__ W1,
    unsigned short* __restrict__ wt)
{
    __shared__ float wtile[32][33];
    int tid = threadIdx.x;
    if (blockIdx.x >= 128) {             // ---- W transpose path
        int wid = blockIdx.x - 128;      // 0..71
        int mat = wid / 36, rem2 = wid % 36;
        int k0 = (rem2 / 6) * 32, n0 = (rem2 % 6) * 32;
        const float* W = mat ? W1 : W0;
#pragma unroll
        for (int p = 0; p < 4; ++p) {
            int idx = p * 64 + tid;
            int k = idx >> 3, n4 = (idx & 7) * 4;
            *(float4*)&wtile[k][n4] =
                *(const float4*)(W + (size_t)(k0 + k) * CF + n0 + n4);
        }
        __syncthreads();
#pragma unroll
        for (int p = 0; p < 4; ++p) {
            int idx = p * 64 + tid;
            int n = idx >> 3, k4 = (idx & 7) * 4;
            ushort4 h;
            h.x = f2bf(wtile[k4 + 0][n]); h.y = f2bf(wtile[k4 + 1][n]);
            h.z = f2bf(wtile[k4 + 2][n]); h.w = f2bf(wtile[k4 + 3][n]);
            *(ushort4*)(wt + (size_t)mat * 36864 + (size_t)(n0 + n) * CF + k0 + k4) = h;
        }
        return;
    }
    int q = blockIdx.x * 64 + tid;
    float td[KNN]; int ti[KNN];
#pragma unroll
    for (int j = 0; j < KNN; ++j) { td[j] = __builtin_inff(); ti[j] = -1; }
    for (int s = 0; s < NSPL; ++s) {       // split order = index order (stable)
        size_t base = ((size_t)q * NSPL + s) * KNN;
#pragma unroll
        for (int j0 = 0; j0 < KNN; ++j0) {
            float d = pk_d[base + j0];
            if (!(d < td[KNN - 1])) break;   // lists sorted: rest can't insert
            int id = pk_i[base + j0];
            td[KNN - 1] = d; ti[KNN - 1] = id;
#pragma unroll
            for (int j = KNN - 1; j > 0; --j) {
                if (td[j] < td[j - 1]) {
                    float tf = td[j]; td[j] = td[j - 1]; td[j - 1] = tf;
                    int tn = ti[j]; ti[j] = ti[j - 1]; ti[j - 1] = tn;
                }
            }
        }
    }
#pragma unroll
    for (int j = 0; j < KNN; ++j) {
        int id = ti[j];                   // -1 <=> invalid (d == inf)
        edges[q * KNN + j] = id;
        if (id >= 0 && id != q) atomicAdd(&deg[id], 1);
    }
}

// ---------------------------------------------------------------- fused Tx1 + out GEMM (MFMA)
// One block per 16-row stripe (512 blocks). out = A0@W0 + A1@W1 + bias via
// mfma_f32_16x16x32_bf16, K=384 fused. A-frag: A[m=lane&15][k=quad*8+j]
// (row-major LDS, rows padded to 200 -> 2-way banks = free). B-frag:
// W^T[n=lane&15][k] row-major from the precomputed wt. C/D (m89-verified):
// col=lane&15, row=(lane>>4)*4+reg. Wave w owns n-tiles {3w..3w+2}.
__global__ __launch_bounds__(256, 2) void out_kernel(
    const unsigned short* __restrict__ xh, const unsigned short* __restrict__ wt,
    const int* __restrict__ edges, const int* __restrict__ deg,
    const float* __restrict__ bias, float* __restrict__ out)
{
    __shared__ unsigned short A0s[16][200];     // xf rows   (6400 B, padded)
    __shared__ unsigned short A1s[16][200];     // Tx1 rows  (6400 B, padded)
    __shared__ unsigned short Wts[2][CF][32];   // W^T k-slice (24576 B)
    __shared__ float coef_s[16][KNN];
    __shared__ int   nb_s[16][KNN];

    int r0 = blockIdx.x * 16;
    int tid = threadIdx.x;

    // stage xf rows (bf16 copy): 16 x 24 uint4 = 384
    for (int t = tid; t < 384; t += 256) {
        int i = t / 24, c8 = (t % 24) * 8;
        *(uint4*)&A0s[i][c8] = *(const uint4*)(xh + (size_t)(r0 + i) * CF + c8);
    }
    // coefficients: one (row, edge) per thread
    if (tid < 16 * KNN) {
        int i = tid / KNN, j = tid % KNN;
        int q = r0 + i;
        int id = edges[q * KNN + j];
        float cf = 0.0f; int s = q;
        if (id >= 0 && id != q) { cf = -disf(deg[id]) * disf(deg[q]); s = id; }
        coef_s[i][j] = cf; nb_s[i][j] = s;
    }
    __syncthreads();
    // gather Tx1 rows from bf16 -> bf16 pairs: 1536 pairs
    for (int e = tid; e < 16 * CF / 2; e += 256) {
        int i = e / 96, c2 = (e % 96) * 2;
        float a0 = 0.0f, a1 = 0.0f;
#pragma unroll
        for (int t = 0; t < KNN; ++t) {
            const unsigned short* row = xh + (size_t)nb_s[i][t] * CF + c2;
            float cf = coef_s[i][t];
            a0 = fmaf(cf, bf2f(row[0]), a0);
            a1 = fmaf(cf, bf2f(row[1]), a1);
        }
        ushort2 h; h.x = f2bf(a0); h.y = f2bf(a1);
        *(ushort2*)&A1s[i][c2] = h;
    }

    int lane = tid & 63, w = tid >> 6;
    int m = lane & 15;                   // A row / B col index
    int kq = (lane >> 4) * 8;            // k offset within 32-slice
    f32x4 acc[3];
#pragma unroll
    for (int t = 0; t < 3; ++t)
#pragma unroll
        for (int r = 0; r < 4; ++r) acc[t][r] = 0.0f;

    for (int kt = 0; kt < 6; ++kt) {     // K=192 in 32-slices, both mats fused
        __syncthreads();                 // kt=0: A1s ready; else Wts consumed
#pragma unroll
        for (int p = 0; p < 6; ++p) {    // stage Wts: 1536 uint4
            int f = p * 256 + tid;
            int mat = f / 768, n = (f % 768) / 4, k16 = (f % 4) * 8;
            *(uint4*)&Wts[mat][n][k16] =
                *(const uint4*)(wt + (size_t)mat * 36864 + (size_t)n * CF + kt * 32 + k16);
        }
        __syncthreads();
        v8bf a0 = *(const v8bf*)&A0s[m][kt * 32 + kq];
        v8bf a1 = *(const v8bf*)&A1s[m][kt * 32 + kq];
#pragma unroll
        for (int t3 = 0; t3 < 3; ++t3) {
            int n0 = w * 48 + t3 * 16;
            v8bf w0 = *(const v8bf*)&Wts[0][n0 + m][kq];
            v8bf w1 = *(const v8bf*)&Wts[1][n0 + m][kq];
            acc[t3] = __builtin_amdgcn_mfma_f32_16x16x32_bf16(a0, w0, acc[t3], 0, 0, 0);
            acc[t3] = __builtin_amdgcn_mfma_f32_16x16x32_bf16(a1, w1, acc[t3], 0, 0, 0);
        }
    }

    int col = lane & 15, rb = (lane >> 4) * 4;
#pragma unroll
    for (int t3 = 0; t3 < 3; ++t3) {
        int n0 = w * 48 + t3 * 16;
        float bv = bias[n0 + col];
#pragma unroll
        for (int r = 0; r < 4; ++r)
            out[(size_t)(r0 + rb + r) * CF + n0 + col] = acc[t3][r] + bv;
    }
}

// ---------------------------------------------------------------- launch
extern "C" void kernel_launch(void* const* d_in, const int* in_sizes, int n_in,
                              void* d_out, int out_size, void* d_ws, size_t ws_size,
                              hipStream_t stream)
{
    const float* x    = (const float*)d_in[0];
    const float* W0   = (const float*)d_in[1];
    const float* W1   = (const float*)d_in[2];
    const float* bias = (const float*)d_in[3];
    float* out = (float*)d_out;

    // Workspace: 6,651,904 B (known-safe total).
    char* ws = (char*)d_ws;
    unsigned short* xh = (unsigned short*)ws; ws += (size_t)NN * CF * 2;  // 3,145,728
    unsigned short* xl = (unsigned short*)ws; ws += (size_t)NN * CF * 2;  // 3,145,728
    float* sq    = (float*)ws;  ws += (size_t)NN * 4;        //    32,768
    int*   deg   = (int*)ws;    ws += (size_t)NN * 4;        //    32,768
    int*   edges = (int*)ws;    ws += (size_t)NN * KNN * 4;  //   294,912

    // xl is dead after knn -> reuse its space for bf16 W0^T/W1^T (147 KB).
    unsigned short* wt = xl;

    // Partial top-k lists live in d_out (2.36 MB of its 6.29 MB); d_out is
    // fully overwritten by out_kernel afterwards, every call.
    float* pk_d = out;                                       // NN*NSPL*KNN
    int*   pk_i = (int*)(out + (size_t)NN * NSPL * KNN);     // NN*NSPL*KNN

    hipLaunchKernelGGL(transpose_kernel, dim3(8, 16), dim3(256), 0, stream,
                       x, xh, xl, sq, deg);
    hipLaunchKernelGGL(knn_kernel, dim3(576), dim3(256), 0, stream,
                       xh, xl, sq, pk_d, pk_i);
    hipLaunchKernelGGL(merge_kernel, dim3(200), dim3(64), 0, stream,
                       pk_d, pk_i, edges, deg, W0, W1, wt);
    hipLaunchKernelGGL(out_kernel, dim3(512), dim3(256), 0, stream,
                       xh, wt, edges, deg, bias, out);
}